// Round 7
// baseline (1097.875 us; speedup 1.0000x reference)
//
#include <hip/hip_runtime.h>

typedef unsigned short u16;
typedef unsigned int u32;

#define E_TOT 202752   // B*N0*DEG = 32*1584*4
#define NMAX  50688    // B*N0
#define HEADS 4
#define B_    32

#define CDIV(a,b) (((a)+(b)-1)/(b))

// order-preserving float->uint map (monotonic); code 0 is below any real float's code
__device__ __forceinline__ u32 ford(float f) {
  u32 u = __float_as_uint(f);
  return (u & 0x80000000u) ? ~u : (u | 0x80000000u);
}
__device__ __forceinline__ float ford_inv(u32 u) {
  u32 b = (u & 0x80000000u) ? (u ^ 0x80000000u) : ~u;
  return __uint_as_float(b);
}

__global__ void k_edge_init(const int* __restrict__ ei, int* __restrict__ src,
                            int* __restrict__ dst, int* __restrict__ em) {
  int e = blockIdx.x * blockDim.x + threadIdx.x;
  if (e >= E_TOT) return;
  src[e] = ei[e];
  dst[e] = ei[E_TOT + e];
  em[e] = 1;
}

// ---------- node transform, 8 nodes/block, W columns reused in regs ----------
template <int FIN>
__global__ void k_transform_t(const float* __restrict__ hin,
                              const float* __restrict__ Wl, const float* __restrict__ bl,
                              const float* __restrict__ Wr, const float* __restrict__ br,
                              float* __restrict__ xl, float* __restrict__ xr) {
  __shared__ float xs[8][FIN];
  int n0 = blockIdx.x * 8, j = threadIdx.x;   // 256 threads
  for (int t = j; t < 8 * FIN; t += 256)
    xs[t >> (FIN == 32 ? 5 : 6)][t & (FIN - 1)] =
        hin[(size_t)(n0 + (t >> (FIN == 32 ? 5 : 6))) * FIN + (t & (FIN - 1))];
  __syncthreads();
  float al[8], ar[8];
  float blv = bl[j], brv = br[j];
#pragma unroll
  for (int t = 0; t < 8; ++t) { al[t] = blv; ar[t] = brv; }
  for (int i = 0; i < FIN; ++i) {
    float wl = Wl[i * 256 + j], wr = Wr[i * 256 + j];
#pragma unroll
    for (int t = 0; t < 8; ++t) {
      float xv = xs[t][i];
      al[t] += xv * wl;
      ar[t] += xv * wr;
    }
  }
#pragma unroll
  for (int t = 0; t < 8; ++t) {
    xl[(size_t)(n0 + t) * 256 + j] = al[t];
    xr[(size_t)(n0 + t) * 256 + j] = ar[t];
  }
}

// ---------- wave-per-edge logits: lane = (head, chan-group-of-4), float4 loads ----------
__global__ void k_logits_w(const int* __restrict__ src, const int* __restrict__ dst,
                           const int* __restrict__ em, const float* __restrict__ ea,
                           const float* __restrict__ We, const float* __restrict__ att,
                           const float* __restrict__ xl, const float* __restrict__ xr,
                           float* __restrict__ lg, u32* __restrict__ mxI) {
  int e = blockIdx.x * 4 + (threadIdx.x >> 6);   // 4 waves/block, 1 edge/wave (E%4==0)
  int lane = threadIdx.x & 63;
  int h = lane >> 4, cg = lane & 15;
  if (!em[e]) { if (cg == 0) lg[e * 4 + h] = 0.f; return; }
  float eav[8];
#pragma unroll
  for (int d = 0; d < 8; ++d) eav[d] = ea[e * 8 + d];   // same addr all lanes: broadcast
  int cb = h * 64 + cg * 4;                              // lane covers channels cb..cb+3
  int dn = dst[e];
  float4 xs4 = *(const float4*)(xl + (size_t)src[e] * 256 + cb);  // 16B/lane coalesced
  float4 xd4 = *(const float4*)(xr + (size_t)dn * 256 + cb);
  float4 at4 = *(const float4*)(att + cb);
  float e0 = 0.f, e1 = 0.f, e2 = 0.f, e3 = 0.f;
#pragma unroll
  for (int d = 0; d < 8; ++d) {
    float4 w4 = *(const float4*)(We + d * 256 + cb);
    e0 += eav[d] * w4.x; e1 += eav[d] * w4.y;
    e2 += eav[d] * w4.z; e3 += eav[d] * w4.w;
  }
  float m0 = xs4.x + xd4.x + e0; m0 = (m0 >= 0.f) ? m0 : 0.2f * m0;
  float m1 = xs4.y + xd4.y + e1; m1 = (m1 >= 0.f) ? m1 : 0.2f * m1;
  float m2 = xs4.z + xd4.z + e2; m2 = (m2 >= 0.f) ? m2 : 0.2f * m2;
  float m3 = xs4.w + xd4.w + e3; m3 = (m3 >= 0.f) ? m3 : 0.2f * m3;
  float v = at4.x * m0 + at4.y * m1 + at4.z * m2 + at4.w * m3;
  v += __shfl_xor(v, 1, 64);
  v += __shfl_xor(v, 2, 64);
  v += __shfl_xor(v, 4, 64);
  v += __shfl_xor(v, 8, 64);        // 16-lane head-group reduction
  if (cg == 0) {
    lg[e * 4 + h] = v;
    atomicMax(&mxI[dn * 4 + h], ford(v));
  }
}

// exp with inline ford-decode of the max; 1 thread/edge, float4 lg
__global__ void k_exp(const int* __restrict__ dst, const int* __restrict__ em,
                      float* __restrict__ lg, const u32* __restrict__ mxI,
                      float* __restrict__ den) {
  int e = blockIdx.x * blockDim.x + threadIdx.x;
  if (e >= E_TOT) return;
  float4* lgp = (float4*)(lg + e * 4);
  if (!em[e]) { *lgp = float4{0.f, 0.f, 0.f, 0.f}; return; }
  int dn = dst[e];
  float4 l4 = *lgp;
  u32 u0 = mxI[dn * 4 + 0], u1 = mxI[dn * 4 + 1], u2 = mxI[dn * 4 + 2], u3 = mxI[dn * 4 + 3];
  l4.x = expf(l4.x - ((u0 == 0u) ? 0.f : ford_inv(u0)));
  l4.y = expf(l4.y - ((u1 == 0u) ? 0.f : ford_inv(u1)));
  l4.z = expf(l4.z - ((u2 == 0u) ? 0.f : ford_inv(u2)));
  l4.w = expf(l4.w - ((u3 == 0u) ? 0.f : ford_inv(u3)));
  *lgp = l4;
  atomicAdd(&den[dn * 4 + 0], l4.x);
  atomicAdd(&den[dn * 4 + 1], l4.y);
  atomicAdd(&den[dn * 4 + 2], l4.z);
  atomicAdd(&den[dn * 4 + 3], l4.w);
}

// ---------- accumulation: 16 lanes/edge, float4 loads, 4 edges/wave ----------
// acc[dst, c] += sum_h 0.25*ex/den * xl[src, h*64+c]
__global__ void k_accum_w(const int* __restrict__ src, const int* __restrict__ dst,
                          const int* __restrict__ em, const float* __restrict__ lg,
                          const float* __restrict__ den, const float* __restrict__ xl,
                          float* __restrict__ acc) {
  int e = blockIdx.x * 16 + (threadIdx.x >> 4);   // E%16==0
  int cg = threadIdx.x & 15;
  if (!em[e]) return;
  int sn = src[e], dn = dst[e];
  const float4* xp = (const float4*)(xl + (size_t)sn * 256);
  float sx = 0.f, sy = 0.f, sz = 0.f, sw = 0.f;
#pragma unroll
  for (int h = 0; h < 4; ++h) {
    float a = 0.25f * lg[e * 4 + h] / fmaxf(den[dn * 4 + h], 1e-16f);  // broadcast loads
    float4 x4 = xp[h * 16 + cg];                                       // 16B coalesced
    sx += a * x4.x; sy += a * x4.y; sz += a * x4.z; sw += a * x4.w;
  }
  float* ap = acc + (size_t)dn * 64 + cg * 4;
  atomicAdd(ap + 0, sx); atomicAdd(ap + 1, sy);
  atomicAdd(ap + 2, sz); atomicAdd(ap + 3, sw);
}

// relu(acc+b) in place, then topk score s = tanh(h.w/||w||)
__global__ void k_nodeout_score(float* __restrict__ acc, const float* __restrict__ b,
                                const float* __restrict__ w, float* __restrict__ s, int N) {
  int n = blockIdx.x * blockDim.x + threadIdx.x;
  if (n >= N) return;
  float dot = 0.f, wn = 0.f;
  float* row = acc + (size_t)n * 64;
  for (int c = 0; c < 64; ++c) {
    float v = fmaxf(row[c] + b[c], 0.f);
    row[c] = v;
    float wv = w[c];
    dot += v * wv;
    wn += wv * wv;
  }
  s[n] = tanhf(dot / sqrtf(wn));
}

// stable descending sort per graph (bitonic on <=2048 padded), emit perm + new_id
__global__ __launch_bounds__(1024) void k_topk(const float* __restrict__ s, int n_per,
                                               int k, int npad,
                                               int* __restrict__ perm, int* __restrict__ new_id) {
  __shared__ float sv[2048];
  __shared__ int si[2048];
  int b = blockIdx.x, tid = threadIdx.x;
  int base = b * n_per;
  for (int i = tid; i < n_per; i += 1024) new_id[base + i] = -1;
  for (int i = tid; i < npad; i += 1024) {
    if (i < n_per) { sv[i] = s[base + i]; si[i] = i; }
    else { sv[i] = -INFINITY; si[i] = i; }
  }
  __syncthreads();
  for (int kk = 2; kk <= npad; kk <<= 1) {
    for (int j = kk >> 1; j > 0; j >>= 1) {
      for (int i = tid; i < npad; i += 1024) {
        int ixj = i ^ j;
        if (ixj > i) {
          float sa = sv[i], sb = sv[ixj];
          int ia = si[i], ib = si[ixj];
          bool after = (sa < sb) || (sa == sb && ia > ib);
          bool doswap = ((i & kk) == 0) ? after : !after;
          if (doswap) { sv[i] = sb; sv[ixj] = sa; si[i] = ib; si[ixj] = ia; }
        }
      }
      __syncthreads();
    }
  }
  for (int r = tid; r < k; r += 1024) {
    int old = si[r];
    perm[b * k + r] = base + old;
    new_id[base + old] = b * k + r;
  }
}

__global__ void k_gather(const float* __restrict__ hin, const float* __restrict__ s,
                         const int* __restrict__ perm, float* __restrict__ hout, int n64) {
  int t = blockIdx.x * blockDim.x + threadIdx.x;
  if (t >= n64) return;
  int i = t >> 6, c = t & 63;
  int g = perm[i];
  hout[t] = hin[(size_t)g * 64 + c] * s[g];
}

__global__ void k_remap(int* __restrict__ src, int* __restrict__ dst,
                        int* __restrict__ em, const int* __restrict__ new_id) {
  int e = blockIdx.x * blockDim.x + threadIdx.x;
  if (e >= E_TOT) return;
  int ns = new_id[src[e]], nd = new_id[dst[e]];
  int m = em[e] && ns >= 0 && nd >= 0;
  src[e] = m ? ns : 0;
  dst[e] = m ? nd : 0;
  em[e] = m;
}

// chunked parallel readout: grid (B, 16), 256 thr
__global__ void k_readout_part(const float* __restrict__ h, int k,
                               float* __restrict__ rsum, u32* __restrict__ rmaxI) {
  __shared__ float ps[256], pm[256];
  int b = blockIdx.x, ch = blockIdx.y, t = threadIdx.x;
  int c = t & 63, rg = t >> 6;
  int rpc = (k + 15) >> 4;
  int start = ch * rpc, end = min(k, start + rpc);
  const float* hb = h + (size_t)b * k * 64;
  float sum = 0.f, mx = -INFINITY;
  for (int i = start + rg; i < end; i += 4) {
    float v = hb[(size_t)i * 64 + c];
    sum += v;
    mx = fmaxf(mx, v);
  }
  ps[t] = sum; pm[t] = mx;
  __syncthreads();
  if (t < 64) {
    float s4 = ps[t] + ps[t + 64] + ps[t + 128] + ps[t + 192];
    float m4 = fmaxf(fmaxf(pm[t], pm[t + 64]), fmaxf(pm[t + 128], pm[t + 192]));
    atomicAdd(&rsum[b * 64 + t], s4);
    atomicMax(&rmaxI[b * 64 + t], ford(m4));
  }
}

__global__ void k_readout_fin(const float* __restrict__ rsum, const u32* __restrict__ rmaxI,
                              int k, float* __restrict__ r) {
  int b = blockIdx.x, c = threadIdx.x;   // 128 threads
  if (c < 64) r[b * 128 + c] += rsum[b * 64 + c] / (float)k;
  else        r[b * 128 + c] += ford_inv(rmaxI[b * 64 + (c - 64)]);
}

__global__ void k_mlp(const float* __restrict__ r,
                      const float* __restrict__ W1, const float* __restrict__ b1,
                      const float* __restrict__ W2, const float* __restrict__ b2,
                      const float* __restrict__ W3, const float* __restrict__ b3,
                      float* __restrict__ out) {
  __shared__ float v0[128], v1[64], v2[64], lgts[16];
  int b = blockIdx.x, t = threadIdx.x;   // 64 threads
  v0[t] = r[b * 128 + t];
  v0[64 + t] = r[b * 128 + 64 + t];
  __syncthreads();
  float a = b1[t];
  for (int i = 0; i < 128; ++i) a += v0[i] * W1[i * 64 + t];
  v1[t] = fmaxf(a, 0.f);
  __syncthreads();
  a = b2[t];
  for (int i = 0; i < 64; ++i) a += v1[i] * W2[i * 64 + t];
  v2[t] = fmaxf(a, 0.f);
  __syncthreads();
  if (t < 16) {
    a = b3[t];
    for (int i = 0; i < 64; ++i) a += v2[i] * W3[i * 16 + t];
    lgts[t] = a;
  }
  __syncthreads();
  if (t == 0) {
    float m = lgts[0];
    for (int j = 1; j < 16; ++j) m = fmaxf(m, lgts[j]);
    float ex[16], sum = 0.f;
    for (int j = 0; j < 16; ++j) { ex[j] = expf(lgts[j] - m); sum += ex[j]; }
    for (int j = 0; j < 16; ++j) out[b * 16 + j] = ex[j] / sum;
  }
}

extern "C" void kernel_launch(void* const* d_in, const int* in_sizes, int n_in,
                              void* d_out, int out_size, void* d_ws, size_t ws_size,
                              hipStream_t stream) {
  (void)in_sizes; (void)n_in; (void)out_size; (void)ws_size;
  const float* x  = (const float*)d_in[0];      // [NMAX, 32] f32
  const float* ea = (const float*)d_in[1];      // [E, 8]     f32
  const int*   ei = (const int*)d_in[2];        // [2, E]

  const float *gWl[3], *gbl[3], *gWr[3], *gbr[3], *gWe[3], *gatt[3], *gb[3], *pw[3];
  for (int l = 0; l < 3; ++l) {
    int p0 = 4 + 7 * l;
    gWl[l]  = (const float*)d_in[p0 + 0];
    gbl[l]  = (const float*)d_in[p0 + 1];
    gWr[l]  = (const float*)d_in[p0 + 2];
    gbr[l]  = (const float*)d_in[p0 + 3];
    gWe[l]  = (const float*)d_in[p0 + 4];
    gatt[l] = (const float*)d_in[p0 + 5];
    gb[l]   = (const float*)d_in[p0 + 6];
    pw[l]   = (const float*)d_in[25 + l];
  }
  const float* fc1W = (const float*)d_in[28];
  const float* fc1b = (const float*)d_in[29];
  const float* fc2W = (const float*)d_in[30];
  const float* fc2b = (const float*)d_in[31];
  const float* fc3W = (const float*)d_in[32];
  const float* fc3b = (const float*)d_in[33];

  // ---- workspace carve (~125.5 MB; proven to fit in rounds 5-6) ----
  char* w = (char*)d_ws;
  size_t off = 0;
  auto alloc = [&](size_t bytes) -> void* {
    void* p = w + off;
    off += (bytes + 255) & ~(size_t)255;
    return p;
  };
  float* hbuf = (float*)alloc((size_t)NMAX * 64 * 4);     // pooled layer input
  float* xl   = (float*)alloc((size_t)NMAX * 256 * 4);    // source transform [N,256]
  float* xr   = (float*)alloc((size_t)NMAX * 256 * 4);    // target transform; acc reuses it
  float* lg   = (float*)alloc((size_t)E_TOT * 4 * 4);     // logits -> exp
  char*  zblk = (char*)alloc((size_t)NMAX * 8 * 4 + 32 * 128 * 4);  // zeroed per layer
  u32*   mxI  = (u32*)zblk;
  float* den  = (float*)(zblk + (size_t)NMAX * 4 * 4);
  float* rsum = (float*)(zblk + (size_t)NMAX * 8 * 4);
  u32*   rmaxI= (u32*)(zblk + (size_t)NMAX * 8 * 4 + 32 * 64 * 4);
  size_t zbytes = (size_t)NMAX * 8 * 4 + 32 * 128 * 4;
  float* sbuf = (float*)alloc((size_t)NMAX * 4);
  float* rbuf = (float*)alloc(32 * 128 * 4);
  int* src    = (int*)alloc((size_t)E_TOT * 4);
  int* dst    = (int*)alloc((size_t)E_TOT * 4);
  int* em     = (int*)alloc((size_t)E_TOT * 4);
  int* new_id = (int*)alloc((size_t)NMAX * 4);
  int* perm   = (int*)alloc((size_t)32 * 1268 * 4);

  k_edge_init<<<CDIV(E_TOT, 256), 256, 0, stream>>>(ei, src, dst, em);
  hipMemsetAsync(rbuf, 0, 32 * 128 * 4, stream);

  const int Ns[3]    = {50688, 40576, 32480};   // B*N0, B*K1, B*K2 (all %8==0)
  const int npers[3] = {1584, 1268, 1015};
  const int ks[3]    = {1268, 1015, 812};
  const int npads[3] = {2048, 2048, 1024};

  for (int l = 0; l < 3; ++l) {
    int N = Ns[l];
    const float* hin = (l == 0) ? x : hbuf;
    hipMemsetAsync(zblk, 0, zbytes, stream);
    if (l == 0)
      k_transform_t<32><<<N / 8, 256, 0, stream>>>(hin, gWl[l], gbl[l], gWr[l], gbr[l], xl, xr);
    else
      k_transform_t<64><<<N / 8, 256, 0, stream>>>(hin, gWl[l], gbl[l], gWr[l], gbr[l], xl, xr);
    k_logits_w<<<E_TOT / 4, 256, 0, stream>>>(src, dst, em, ea, gWe[l], gatt[l],
                                              xl, xr, lg, mxI);
    k_exp<<<CDIV(E_TOT, 256), 256, 0, stream>>>(dst, em, lg, mxI, den);
    float* acc = xr;   // xr dead after logits; reuse as accumulator
    hipMemsetAsync(acc, 0, (size_t)N * 64 * 4, stream);
    k_accum_w<<<E_TOT / 16, 256, 0, stream>>>(src, dst, em, lg, den, xl, acc);
    k_nodeout_score<<<CDIV(N, 256), 256, 0, stream>>>(acc, gb[l], pw[l], sbuf, N);
    k_topk<<<32, 1024, 0, stream>>>(sbuf, npers[l], ks[l], npads[l], perm, new_id);
    k_gather<<<CDIV(B_ * ks[l] * 64, 256), 256, 0, stream>>>(acc, sbuf, perm, hbuf,
                                                             B_ * ks[l] * 64);
    k_remap<<<CDIV(E_TOT, 256), 256, 0, stream>>>(src, dst, em, new_id);
    k_readout_part<<<dim3(32, 16), 256, 0, stream>>>(hbuf, ks[l], rsum, rmaxI);
    k_readout_fin<<<32, 128, 0, stream>>>(rsum, rmaxI, ks[l], rbuf);
  }
  k_mlp<<<32, 64, 0, stream>>>(rbuf, fc1W, fc1b, fc2W, fc2b, fc3W, fc3b, (float*)d_out);
}

// Round 8
// 845.974 us; speedup vs baseline: 1.2978x; 1.2978x over previous
//
#include <hip/hip_runtime.h>

typedef unsigned short u16;
typedef unsigned int u32;

#define E_TOT 202752   // B*N0*DEG = 32*1584*4
#define NMAX  50688    // B*N0
#define HEADS 4
#define B_    32

#define CDIV(a,b) (((a)+(b)-1)/(b))

// order-preserving float->uint map (monotonic); code 0 is below any real float's code
__device__ __forceinline__ u32 ford(float f) {
  u32 u = __float_as_uint(f);
  return (u & 0x80000000u) ? ~u : (u | 0x80000000u);
}
__device__ __forceinline__ float ford_inv(u32 u) {
  u32 b = (u & 0x80000000u) ? (u ^ 0x80000000u) : ~u;
  return __uint_as_float(b);
}

__global__ void k_edge_init(const int* __restrict__ ei, int* __restrict__ src,
                            int* __restrict__ dst, int* __restrict__ em) {
  int e = blockIdx.x * blockDim.x + threadIdx.x;
  if (e >= E_TOT) return;
  src[e] = ei[e];
  dst[e] = ei[E_TOT + e];
  em[e] = 1;
}

// ---------- node transform, 8 nodes/block, W columns reused in regs ----------
template <int FIN>
__global__ void k_transform_t(const float* __restrict__ hin,
                              const float* __restrict__ Wl, const float* __restrict__ bl,
                              const float* __restrict__ Wr, const float* __restrict__ br,
                              float* __restrict__ xl, float* __restrict__ xr) {
  __shared__ float xs[8][FIN];
  int n0 = blockIdx.x * 8, j = threadIdx.x;   // 256 threads
  for (int t = j; t < 8 * FIN; t += 256)
    xs[t >> (FIN == 32 ? 5 : 6)][t & (FIN - 1)] =
        hin[(size_t)(n0 + (t >> (FIN == 32 ? 5 : 6))) * FIN + (t & (FIN - 1))];
  __syncthreads();
  float al[8], ar[8];
  float blv = bl[j], brv = br[j];
#pragma unroll
  for (int t = 0; t < 8; ++t) { al[t] = blv; ar[t] = brv; }
  for (int i = 0; i < FIN; ++i) {
    float wl = Wl[i * 256 + j], wr = Wr[i * 256 + j];
#pragma unroll
    for (int t = 0; t < 8; ++t) {
      float xv = xs[t][i];
      al[t] += xv * wl;
      ar[t] += xv * wr;
    }
  }
#pragma unroll
  for (int t = 0; t < 8; ++t) {
    xl[(size_t)(n0 + t) * 256 + j] = al[t];
    xr[(size_t)(n0 + t) * 256 + j] = ar[t];
  }
}

// ---------- wave-per-edge logits: lane = (head, chan-group-of-4), float4 loads ----------
__global__ void k_logits_w(const int* __restrict__ src, const int* __restrict__ dst,
                           const int* __restrict__ em, const float* __restrict__ ea,
                           const float* __restrict__ We, const float* __restrict__ att,
                           const float* __restrict__ xl, const float* __restrict__ xr,
                           float* __restrict__ lg, u32* __restrict__ mxI) {
  int e = blockIdx.x * 4 + (threadIdx.x >> 6);   // 4 waves/block, 1 edge/wave (E%4==0)
  int lane = threadIdx.x & 63;
  int h = lane >> 4, cg = lane & 15;
  if (!em[e]) { if (cg == 0) lg[e * 4 + h] = 0.f; return; }
  float eav[8];
#pragma unroll
  for (int d = 0; d < 8; ++d) eav[d] = ea[e * 8 + d];   // same addr all lanes: broadcast
  int cb = h * 64 + cg * 4;                              // lane covers channels cb..cb+3
  int dn = dst[e];
  float4 xs4 = *(const float4*)(xl + (size_t)src[e] * 256 + cb);  // 16B/lane coalesced
  float4 xd4 = *(const float4*)(xr + (size_t)dn * 256 + cb);
  float4 at4 = *(const float4*)(att + cb);
  float e0 = 0.f, e1 = 0.f, e2 = 0.f, e3 = 0.f;
#pragma unroll
  for (int d = 0; d < 8; ++d) {
    float4 w4 = *(const float4*)(We + d * 256 + cb);
    e0 += eav[d] * w4.x; e1 += eav[d] * w4.y;
    e2 += eav[d] * w4.z; e3 += eav[d] * w4.w;
  }
  float m0 = xs4.x + xd4.x + e0; m0 = (m0 >= 0.f) ? m0 : 0.2f * m0;
  float m1 = xs4.y + xd4.y + e1; m1 = (m1 >= 0.f) ? m1 : 0.2f * m1;
  float m2 = xs4.z + xd4.z + e2; m2 = (m2 >= 0.f) ? m2 : 0.2f * m2;
  float m3 = xs4.w + xd4.w + e3; m3 = (m3 >= 0.f) ? m3 : 0.2f * m3;
  float v = at4.x * m0 + at4.y * m1 + at4.z * m2 + at4.w * m3;
  v += __shfl_xor(v, 1, 64);
  v += __shfl_xor(v, 2, 64);
  v += __shfl_xor(v, 4, 64);
  v += __shfl_xor(v, 8, 64);        // 16-lane head-group reduction
  if (cg == 0) {
    lg[e * 4 + h] = v;
    atomicMax(&mxI[dn * 4 + h], ford(v));
  }
}

// exp with inline ford-decode of the max; 1 thread/edge, float4 lg
__global__ void k_exp(const int* __restrict__ dst, const int* __restrict__ em,
                      float* __restrict__ lg, const u32* __restrict__ mxI,
                      float* __restrict__ den) {
  int e = blockIdx.x * blockDim.x + threadIdx.x;
  if (e >= E_TOT) return;
  float4* lgp = (float4*)(lg + e * 4);
  if (!em[e]) { *lgp = float4{0.f, 0.f, 0.f, 0.f}; return; }
  int dn = dst[e];
  float4 l4 = *lgp;
  u32 u0 = mxI[dn * 4 + 0], u1 = mxI[dn * 4 + 1], u2 = mxI[dn * 4 + 2], u3 = mxI[dn * 4 + 3];
  l4.x = expf(l4.x - ((u0 == 0u) ? 0.f : ford_inv(u0)));
  l4.y = expf(l4.y - ((u1 == 0u) ? 0.f : ford_inv(u1)));
  l4.z = expf(l4.z - ((u2 == 0u) ? 0.f : ford_inv(u2)));
  l4.w = expf(l4.w - ((u3 == 0u) ? 0.f : ford_inv(u3)));
  *lgp = l4;
  atomicAdd(&den[dn * 4 + 0], l4.x);
  atomicAdd(&den[dn * 4 + 1], l4.y);
  atomicAdd(&den[dn * 4 + 2], l4.z);
  atomicAdd(&den[dn * 4 + 3], l4.w);
}

// ---------- wave-per-edge accumulation: lane = channel, ONE coalesced atomic row ----------
// acc[dst, c] += sum_h 0.25*ex/den * xl[src, h*64+c]
__global__ void k_accum_w(const int* __restrict__ src, const int* __restrict__ dst,
                          const int* __restrict__ em, const float* __restrict__ lg,
                          const float* __restrict__ den, const float* __restrict__ xl,
                          float* __restrict__ acc) {
  int e = blockIdx.x * 4 + (threadIdx.x >> 6);   // 4 waves/block, 1 edge/wave
  int lane = threadIdx.x & 63;
  if (!em[e]) return;
  int sn = src[e], dn = dst[e];
  const float* xp = xl + (size_t)sn * 256;
  float s = 0.f;
#pragma unroll
  for (int h = 0; h < 4; ++h) {
    float a = 0.25f * lg[e * 4 + h] / fmaxf(den[dn * 4 + h], 1e-16f);  // broadcast loads
    s += a * xp[h * 64 + lane];                                        // coalesced 256B
  }
  atomicAdd(&acc[(size_t)dn * 64 + lane], s);   // 64 contiguous atomics in one instr
}

// relu(acc+b) in place, then topk score s = tanh(h.w/||w||)
__global__ void k_nodeout_score(float* __restrict__ acc, const float* __restrict__ b,
                                const float* __restrict__ w, float* __restrict__ s, int N) {
  int n = blockIdx.x * blockDim.x + threadIdx.x;
  if (n >= N) return;
  float dot = 0.f, wn = 0.f;
  float* row = acc + (size_t)n * 64;
  for (int c = 0; c < 64; ++c) {
    float v = fmaxf(row[c] + b[c], 0.f);
    row[c] = v;
    float wv = w[c];
    dot += v * wv;
    wn += wv * wv;
  }
  s[n] = tanhf(dot / sqrtf(wn));
}

// stable descending sort per graph (bitonic on <=2048 padded), emit perm + new_id
__global__ __launch_bounds__(1024) void k_topk(const float* __restrict__ s, int n_per,
                                               int k, int npad,
                                               int* __restrict__ perm, int* __restrict__ new_id) {
  __shared__ float sv[2048];
  __shared__ int si[2048];
  int b = blockIdx.x, tid = threadIdx.x;
  int base = b * n_per;
  for (int i = tid; i < n_per; i += 1024) new_id[base + i] = -1;
  for (int i = tid; i < npad; i += 1024) {
    if (i < n_per) { sv[i] = s[base + i]; si[i] = i; }
    else { sv[i] = -INFINITY; si[i] = i; }
  }
  __syncthreads();
  for (int kk = 2; kk <= npad; kk <<= 1) {
    for (int j = kk >> 1; j > 0; j >>= 1) {
      for (int i = tid; i < npad; i += 1024) {
        int ixj = i ^ j;
        if (ixj > i) {
          float sa = sv[i], sb = sv[ixj];
          int ia = si[i], ib = si[ixj];
          bool after = (sa < sb) || (sa == sb && ia > ib);
          bool doswap = ((i & kk) == 0) ? after : !after;
          if (doswap) { sv[i] = sb; sv[ixj] = sa; si[i] = ib; si[ixj] = ia; }
        }
      }
      __syncthreads();
    }
  }
  for (int r = tid; r < k; r += 1024) {
    int old = si[r];
    perm[b * k + r] = base + old;
    new_id[base + old] = b * k + r;
  }
}

__global__ void k_gather(const float* __restrict__ hin, const float* __restrict__ s,
                         const int* __restrict__ perm, float* __restrict__ hout, int n64) {
  int t = blockIdx.x * blockDim.x + threadIdx.x;
  if (t >= n64) return;
  int i = t >> 6, c = t & 63;
  int g = perm[i];
  hout[t] = hin[(size_t)g * 64 + c] * s[g];
}

__global__ void k_remap(int* __restrict__ src, int* __restrict__ dst,
                        int* __restrict__ em, const int* __restrict__ new_id) {
  int e = blockIdx.x * blockDim.x + threadIdx.x;
  if (e >= E_TOT) return;
  int ns = new_id[src[e]], nd = new_id[dst[e]];
  int m = em[e] && ns >= 0 && nd >= 0;
  src[e] = m ? ns : 0;
  dst[e] = m ? nd : 0;
  em[e] = m;
}

// chunked parallel readout: grid (B, 16), 256 thr
__global__ void k_readout_part(const float* __restrict__ h, int k,
                               float* __restrict__ rsum, u32* __restrict__ rmaxI) {
  __shared__ float ps[256], pm[256];
  int b = blockIdx.x, ch = blockIdx.y, t = threadIdx.x;
  int c = t & 63, rg = t >> 6;
  int rpc = (k + 15) >> 4;
  int start = ch * rpc, end = min(k, start + rpc);
  const float* hb = h + (size_t)b * k * 64;
  float sum = 0.f, mx = -INFINITY;
  for (int i = start + rg; i < end; i += 4) {
    float v = hb[(size_t)i * 64 + c];
    sum += v;
    mx = fmaxf(mx, v);
  }
  ps[t] = sum; pm[t] = mx;
  __syncthreads();
  if (t < 64) {
    float s4 = ps[t] + ps[t + 64] + ps[t + 128] + ps[t + 192];
    float m4 = fmaxf(fmaxf(pm[t], pm[t + 64]), fmaxf(pm[t + 128], pm[t + 192]));
    atomicAdd(&rsum[b * 64 + t], s4);
    atomicMax(&rmaxI[b * 64 + t], ford(m4));
  }
}

__global__ void k_readout_fin(const float* __restrict__ rsum, const u32* __restrict__ rmaxI,
                              int k, float* __restrict__ r) {
  int b = blockIdx.x, c = threadIdx.x;   // 128 threads
  if (c < 64) r[b * 128 + c] += rsum[b * 64 + c] / (float)k;
  else        r[b * 128 + c] += ford_inv(rmaxI[b * 64 + (c - 64)]);
}

__global__ void k_mlp(const float* __restrict__ r,
                      const float* __restrict__ W1, const float* __restrict__ b1,
                      const float* __restrict__ W2, const float* __restrict__ b2,
                      const float* __restrict__ W3, const float* __restrict__ b3,
                      float* __restrict__ out) {
  __shared__ float v0[128], v1[64], v2[64], lgts[16];
  int b = blockIdx.x, t = threadIdx.x;   // 64 threads
  v0[t] = r[b * 128 + t];
  v0[64 + t] = r[b * 128 + 64 + t];
  __syncthreads();
  float a = b1[t];
  for (int i = 0; i < 128; ++i) a += v0[i] * W1[i * 64 + t];
  v1[t] = fmaxf(a, 0.f);
  __syncthreads();
  a = b2[t];
  for (int i = 0; i < 64; ++i) a += v1[i] * W2[i * 64 + t];
  v2[t] = fmaxf(a, 0.f);
  __syncthreads();
  if (t < 16) {
    a = b3[t];
    for (int i = 0; i < 64; ++i) a += v2[i] * W3[i * 16 + t];
    lgts[t] = a;
  }
  __syncthreads();
  if (t == 0) {
    float m = lgts[0];
    for (int j = 1; j < 16; ++j) m = fmaxf(m, lgts[j]);
    float ex[16], sum = 0.f;
    for (int j = 0; j < 16; ++j) { ex[j] = expf(lgts[j] - m); sum += ex[j]; }
    for (int j = 0; j < 16; ++j) out[b * 16 + j] = ex[j] / sum;
  }
}

extern "C" void kernel_launch(void* const* d_in, const int* in_sizes, int n_in,
                              void* d_out, int out_size, void* d_ws, size_t ws_size,
                              hipStream_t stream) {
  (void)in_sizes; (void)n_in; (void)out_size; (void)ws_size;
  const float* x  = (const float*)d_in[0];      // [NMAX, 32] f32
  const float* ea = (const float*)d_in[1];      // [E, 8]     f32
  const int*   ei = (const int*)d_in[2];        // [2, E]

  const float *gWl[3], *gbl[3], *gWr[3], *gbr[3], *gWe[3], *gatt[3], *gb[3], *pw[3];
  for (int l = 0; l < 3; ++l) {
    int p0 = 4 + 7 * l;
    gWl[l]  = (const float*)d_in[p0 + 0];
    gbl[l]  = (const float*)d_in[p0 + 1];
    gWr[l]  = (const float*)d_in[p0 + 2];
    gbr[l]  = (const float*)d_in[p0 + 3];
    gWe[l]  = (const float*)d_in[p0 + 4];
    gatt[l] = (const float*)d_in[p0 + 5];
    gb[l]   = (const float*)d_in[p0 + 6];
    pw[l]   = (const float*)d_in[25 + l];
  }
  const float* fc1W = (const float*)d_in[28];
  const float* fc1b = (const float*)d_in[29];
  const float* fc2W = (const float*)d_in[30];
  const float* fc2b = (const float*)d_in[31];
  const float* fc3W = (const float*)d_in[32];
  const float* fc3b = (const float*)d_in[33];

  // ---- workspace carve (~125.5 MB; proven to fit in rounds 5-7) ----
  char* w = (char*)d_ws;
  size_t off = 0;
  auto alloc = [&](size_t bytes) -> void* {
    void* p = w + off;
    off += (bytes + 255) & ~(size_t)255;
    return p;
  };
  float* hbuf = (float*)alloc((size_t)NMAX * 64 * 4);     // pooled layer input
  float* xl   = (float*)alloc((size_t)NMAX * 256 * 4);    // source transform [N,256]
  float* xr   = (float*)alloc((size_t)NMAX * 256 * 4);    // target transform; acc reuses it
  float* lg   = (float*)alloc((size_t)E_TOT * 4 * 4);     // logits -> exp
  char*  zblk = (char*)alloc((size_t)NMAX * 8 * 4 + 32 * 128 * 4);  // zeroed per layer
  u32*   mxI  = (u32*)zblk;
  float* den  = (float*)(zblk + (size_t)NMAX * 4 * 4);
  float* rsum = (float*)(zblk + (size_t)NMAX * 8 * 4);
  u32*   rmaxI= (u32*)(zblk + (size_t)NMAX * 8 * 4 + 32 * 64 * 4);
  size_t zbytes = (size_t)NMAX * 8 * 4 + 32 * 128 * 4;
  float* sbuf = (float*)alloc((size_t)NMAX * 4);
  float* rbuf = (float*)alloc(32 * 128 * 4);
  int* src    = (int*)alloc((size_t)E_TOT * 4);
  int* dst    = (int*)alloc((size_t)E_TOT * 4);
  int* em     = (int*)alloc((size_t)E_TOT * 4);
  int* new_id = (int*)alloc((size_t)NMAX * 4);
  int* perm   = (int*)alloc((size_t)32 * 1268 * 4);

  k_edge_init<<<CDIV(E_TOT, 256), 256, 0, stream>>>(ei, src, dst, em);
  hipMemsetAsync(rbuf, 0, 32 * 128 * 4, stream);

  const int Ns[3]    = {50688, 40576, 32480};   // B*N0, B*K1, B*K2 (all %8==0)
  const int npers[3] = {1584, 1268, 1015};
  const int ks[3]    = {1268, 1015, 812};
  const int npads[3] = {2048, 2048, 1024};

  for (int l = 0; l < 3; ++l) {
    int N = Ns[l];
    const float* hin = (l == 0) ? x : hbuf;
    hipMemsetAsync(zblk, 0, zbytes, stream);
    if (l == 0)
      k_transform_t<32><<<N / 8, 256, 0, stream>>>(hin, gWl[l], gbl[l], gWr[l], gbr[l], xl, xr);
    else
      k_transform_t<64><<<N / 8, 256, 0, stream>>>(hin, gWl[l], gbl[l], gWr[l], gbr[l], xl, xr);
    k_logits_w<<<E_TOT / 4, 256, 0, stream>>>(src, dst, em, ea, gWe[l], gatt[l],
                                              xl, xr, lg, mxI);
    k_exp<<<CDIV(E_TOT, 256), 256, 0, stream>>>(dst, em, lg, mxI, den);
    float* acc = xr;   // xr dead after logits; reuse as accumulator
    hipMemsetAsync(acc, 0, (size_t)N * 64 * 4, stream);
    k_accum_w<<<E_TOT / 4, 256, 0, stream>>>(src, dst, em, lg, den, xl, acc);
    k_nodeout_score<<<CDIV(N, 256), 256, 0, stream>>>(acc, gb[l], pw[l], sbuf, N);
    k_topk<<<32, 1024, 0, stream>>>(sbuf, npers[l], ks[l], npads[l], perm, new_id);
    k_gather<<<CDIV(B_ * ks[l] * 64, 256), 256, 0, stream>>>(acc, sbuf, perm, hbuf,
                                                             B_ * ks[l] * 64);
    k_remap<<<CDIV(E_TOT, 256), 256, 0, stream>>>(src, dst, em, new_id);
    k_readout_part<<<dim3(32, 16), 256, 0, stream>>>(hbuf, ks[l], rsum, rmaxI);
    k_readout_fin<<<32, 128, 0, stream>>>(rsum, rmaxI, ks[l], rbuf);
  }
  k_mlp<<<32, 64, 0, stream>>>(rbuf, fc1W, fc1b, fc2W, fc2b, fc3W, fc3b, (float*)d_out);
}

// Round 9
// 594.439 us; speedup vs baseline: 1.8469x; 1.4231x over previous
//
#include <hip/hip_runtime.h>

typedef unsigned short u16;
typedef unsigned int u32;

#define E_TOT 202752   // B*N0*DEG = 32*1584*4
#define NMAX  50688    // B*N0
#define HEADS 4
#define B_    32
#define MAXDEG 32      // Poisson(4) in-degree: P(>=32) ~ 1e-18/node — safe bucket

#define CDIV(a,b) (((a)+(b)-1)/(b))

// order-preserving float->uint map (monotonic); code 0 is below any real float's code
__device__ __forceinline__ u32 ford(float f) {
  u32 u = __float_as_uint(f);
  return (u & 0x80000000u) ? ~u : (u | 0x80000000u);
}
__device__ __forceinline__ float ford_inv(u32 u) {
  u32 b = (u & 0x80000000u) ? (u ^ 0x80000000u) : ~u;
  return __uint_as_float(b);
}

__global__ void k_edge_init(const int* __restrict__ ei, int* __restrict__ src,
                            int* __restrict__ dst, int* __restrict__ em) {
  int e = blockIdx.x * blockDim.x + threadIdx.x;
  if (e >= E_TOT) return;
  src[e] = ei[e];
  dst[e] = ei[E_TOT + e];
  em[e] = 1;
}

// ---------- node transform, 8 nodes/block, W columns reused in regs ----------
template <int FIN>
__global__ void k_transform_t(const float* __restrict__ hin,
                              const float* __restrict__ Wl, const float* __restrict__ bl,
                              const float* __restrict__ Wr, const float* __restrict__ br,
                              float* __restrict__ xl, float* __restrict__ xr) {
  __shared__ float xs[8][FIN];
  int n0 = blockIdx.x * 8, j = threadIdx.x;   // 256 threads
  for (int t = j; t < 8 * FIN; t += 256)
    xs[t >> (FIN == 32 ? 5 : 6)][t & (FIN - 1)] =
        hin[(size_t)(n0 + (t >> (FIN == 32 ? 5 : 6))) * FIN + (t & (FIN - 1))];
  __syncthreads();
  float al[8], ar[8];
  float blv = bl[j], brv = br[j];
#pragma unroll
  for (int t = 0; t < 8; ++t) { al[t] = blv; ar[t] = brv; }
  for (int i = 0; i < FIN; ++i) {
    float wl = Wl[i * 256 + j], wr = Wr[i * 256 + j];
#pragma unroll
    for (int t = 0; t < 8; ++t) {
      float xv = xs[t][i];
      al[t] += xv * wl;
      ar[t] += xv * wr;
    }
  }
#pragma unroll
  for (int t = 0; t < 8; ++t) {
    xl[(size_t)(n0 + t) * 256 + j] = al[t];
    xr[(size_t)(n0 + t) * 256 + j] = ar[t];
  }
}

// ---------- bucketed CSR build: csr[dst*MAXDEG + pos] = edge id ----------
__global__ void k_csr_build(const int* __restrict__ dst, const int* __restrict__ em,
                            int* __restrict__ cnt, int* __restrict__ csr) {
  int e = blockIdx.x * blockDim.x + threadIdx.x;
  if (e >= E_TOT || !em[e]) return;
  int dn = dst[e];
  int pos = atomicAdd(&cnt[dn], 1);
  if (pos < MAXDEG) csr[dn * MAXDEG + pos] = e;
}

// ---------- fused GATv2 per dst node: logits + online softmax + accum + bias/relu + score ----
// one 64-lane wave per node; lane = (head h = lane>>4, chan-group cg = lane&15)
__global__ void k_gat_fused(const int* __restrict__ srcv, const int* __restrict__ cnt,
                            const int* __restrict__ csr, const float* __restrict__ ea,
                            const float* __restrict__ We, const float* __restrict__ att,
                            const float* __restrict__ xl, const float* __restrict__ xr,
                            const float* __restrict__ bias, const float* __restrict__ pwv,
                            float* __restrict__ out, float* __restrict__ sc, int N) {
  int n = blockIdx.x * 4 + (threadIdx.x >> 6);   // 4 waves/block (N%4==0)
  int lane = threadIdx.x & 63;
  int cg = lane & 15;
  int cb = (lane >> 4) * 64 + cg * 4;            // this lane's 4 channels
  if (n >= N) return;
  int deg = min(cnt[n], MAXDEG);
  float4 xd4 = *(const float4*)(xr + (size_t)n * 256 + cb);
  float4 at4 = *(const float4*)(att + cb);
  // hoist We columns (L1-resident anyway, but regs kill 8 loads/edge)
  float4 w0 = *(const float4*)(We + 0 * 256 + cb);
  float4 w1 = *(const float4*)(We + 1 * 256 + cb);
  float4 w2 = *(const float4*)(We + 2 * 256 + cb);
  float4 w3 = *(const float4*)(We + 3 * 256 + cb);
  float4 w4_ = *(const float4*)(We + 4 * 256 + cb);
  float4 w5 = *(const float4*)(We + 5 * 256 + cb);
  float4 w6 = *(const float4*)(We + 6 * 256 + cb);
  float4 w7 = *(const float4*)(We + 7 * 256 + cb);
  float m = -INFINITY, l = 0.f;
  float ox = 0.f, oy = 0.f, oz = 0.f, ow = 0.f;
  for (int i = 0; i < deg; ++i) {
    int e = csr[n * MAXDEG + i];
    float4 ea0 = *(const float4*)(ea + (size_t)e * 8);       // broadcast (wave-uniform)
    float4 ea1 = *(const float4*)(ea + (size_t)e * 8 + 4);
    float4 xs4 = *(const float4*)(xl + (size_t)srcv[e] * 256 + cb);  // coalesced 1KB/wave
    float e0 = ea0.x * w0.x + ea0.y * w1.x + ea0.z * w2.x + ea0.w * w3.x
             + ea1.x * w4_.x + ea1.y * w5.x + ea1.z * w6.x + ea1.w * w7.x;
    float e1 = ea0.x * w0.y + ea0.y * w1.y + ea0.z * w2.y + ea0.w * w3.y
             + ea1.x * w4_.y + ea1.y * w5.y + ea1.z * w6.y + ea1.w * w7.y;
    float e2 = ea0.x * w0.z + ea0.y * w1.z + ea0.z * w2.z + ea0.w * w3.z
             + ea1.x * w4_.z + ea1.y * w5.z + ea1.z * w6.z + ea1.w * w7.z;
    float e3 = ea0.x * w0.w + ea0.y * w1.w + ea0.z * w2.w + ea0.w * w3.w
             + ea1.x * w4_.w + ea1.y * w5.w + ea1.z * w6.w + ea1.w * w7.w;
    float m0 = xs4.x + xd4.x + e0; m0 = (m0 >= 0.f) ? m0 : 0.2f * m0;  // leaky 0.2
    float m1 = xs4.y + xd4.y + e1; m1 = (m1 >= 0.f) ? m1 : 0.2f * m1;
    float m2 = xs4.z + xd4.z + e2; m2 = (m2 >= 0.f) ? m2 : 0.2f * m2;
    float m3 = xs4.w + xd4.w + e3; m3 = (m3 >= 0.f) ? m3 : 0.2f * m3;
    float v = at4.x * m0 + at4.y * m1 + at4.z * m2 + at4.w * m3;
    v += __shfl_xor(v, 1, 64);
    v += __shfl_xor(v, 2, 64);
    v += __shfl_xor(v, 4, 64);
    v += __shfl_xor(v, 8, 64);     // butterfly: all 16 head-lanes hold head logit
    float nm = fmaxf(m, v);
    float scale = __expf(m - nm);  // exp(-inf - x) = 0 handles first edge
    float p = __expf(v - nm);
    ox = ox * scale + p * xs4.x;
    oy = oy * scale + p * xs4.y;
    oz = oz * scale + p * xs4.z;
    ow = ow * scale + p * xs4.w;
    l = l * scale + p;
    m = nm;
  }
  // per-head y = O/den, then 0.25 * head-sum  (deg==0 -> l=0 -> y=0, matches ref)
  float inv = 0.25f / fmaxf(l, 1e-16f);
  float r0 = ox * inv, r1 = oy * inv, r2 = oz * inv, r3 = ow * inv;
  r0 += __shfl_xor(r0, 16, 64); r0 += __shfl_xor(r0, 32, 64);
  r1 += __shfl_xor(r1, 16, 64); r1 += __shfl_xor(r1, 32, 64);
  r2 += __shfl_xor(r2, 16, 64); r2 += __shfl_xor(r2, 32, 64);
  r3 += __shfl_xor(r3, 16, 64); r3 += __shfl_xor(r3, 32, 64);
  float4 bi4 = *(const float4*)(bias + cg * 4);
  r0 = fmaxf(r0 + bi4.x, 0.f); r1 = fmaxf(r1 + bi4.y, 0.f);
  r2 = fmaxf(r2 + bi4.z, 0.f); r3 = fmaxf(r3 + bi4.w, 0.f);
  if (lane < 16) *(float4*)(out + (size_t)n * 64 + cg * 4) = float4{r0, r1, r2, r3};
  // topk score: s = tanh(h.w / ||w||)  (reduce over cg lanes; h-replicas identical)
  float4 pw4 = *(const float4*)(pwv + cg * 4);
  float dot = r0 * pw4.x + r1 * pw4.y + r2 * pw4.z + r3 * pw4.w;
  float wn = pw4.x * pw4.x + pw4.y * pw4.y + pw4.z * pw4.z + pw4.w * pw4.w;
  dot += __shfl_xor(dot, 1, 64); wn += __shfl_xor(wn, 1, 64);
  dot += __shfl_xor(dot, 2, 64); wn += __shfl_xor(wn, 2, 64);
  dot += __shfl_xor(dot, 4, 64); wn += __shfl_xor(wn, 4, 64);
  dot += __shfl_xor(dot, 8, 64); wn += __shfl_xor(wn, 8, 64);
  if (lane == 0) sc[n] = tanhf(dot / sqrtf(wn));
}

// stable descending sort per graph (bitonic on <=2048 padded), emit perm + new_id
__global__ __launch_bounds__(1024) void k_topk(const float* __restrict__ s, int n_per,
                                               int k, int npad,
                                               int* __restrict__ perm, int* __restrict__ new_id) {
  __shared__ float sv[2048];
  __shared__ int si[2048];
  int b = blockIdx.x, tid = threadIdx.x;
  int base = b * n_per;
  for (int i = tid; i < n_per; i += 1024) new_id[base + i] = -1;
  for (int i = tid; i < npad; i += 1024) {
    if (i < n_per) { sv[i] = s[base + i]; si[i] = i; }
    else { sv[i] = -INFINITY; si[i] = i; }
  }
  __syncthreads();
  for (int kk = 2; kk <= npad; kk <<= 1) {
    for (int j = kk >> 1; j > 0; j >>= 1) {
      for (int i = tid; i < npad; i += 1024) {
        int ixj = i ^ j;
        if (ixj > i) {
          float sa = sv[i], sb = sv[ixj];
          int ia = si[i], ib = si[ixj];
          bool after = (sa < sb) || (sa == sb && ia > ib);
          bool doswap = ((i & kk) == 0) ? after : !after;
          if (doswap) { sv[i] = sb; sv[ixj] = sa; si[i] = ib; si[ixj] = ia; }
        }
      }
      __syncthreads();
    }
  }
  for (int r = tid; r < k; r += 1024) {
    int old = si[r];
    perm[b * k + r] = base + old;
    new_id[base + old] = b * k + r;
  }
}

__global__ void k_gather(const float* __restrict__ hin, const float* __restrict__ s,
                         const int* __restrict__ perm, float* __restrict__ hout, int n64) {
  int t = blockIdx.x * blockDim.x + threadIdx.x;
  if (t >= n64) return;
  int i = t >> 6, c = t & 63;
  int g = perm[i];
  hout[t] = hin[(size_t)g * 64 + c] * s[g];
}

__global__ void k_remap(int* __restrict__ src, int* __restrict__ dst,
                        int* __restrict__ em, const int* __restrict__ new_id) {
  int e = blockIdx.x * blockDim.x + threadIdx.x;
  if (e >= E_TOT) return;
  int ns = new_id[src[e]], nd = new_id[dst[e]];
  int m = em[e] && ns >= 0 && nd >= 0;
  src[e] = m ? ns : 0;
  dst[e] = m ? nd : 0;
  em[e] = m;
}

// chunked parallel readout: grid (B, 16), 256 thr
__global__ void k_readout_part(const float* __restrict__ h, int k,
                               float* __restrict__ rsum, u32* __restrict__ rmaxI) {
  __shared__ float ps[256], pm[256];
  int b = blockIdx.x, ch = blockIdx.y, t = threadIdx.x;
  int c = t & 63, rg = t >> 6;
  int rpc = (k + 15) >> 4;
  int start = ch * rpc, end = min(k, start + rpc);
  const float* hb = h + (size_t)b * k * 64;
  float sum = 0.f, mx = -INFINITY;
  for (int i = start + rg; i < end; i += 4) {
    float v = hb[(size_t)i * 64 + c];
    sum += v;
    mx = fmaxf(mx, v);
  }
  ps[t] = sum; pm[t] = mx;
  __syncthreads();
  if (t < 64) {
    float s4 = ps[t] + ps[t + 64] + ps[t + 128] + ps[t + 192];
    float m4 = fmaxf(fmaxf(pm[t], pm[t + 64]), fmaxf(pm[t + 128], pm[t + 192]));
    atomicAdd(&rsum[b * 64 + t], s4);
    atomicMax(&rmaxI[b * 64 + t], ford(m4));
  }
}

__global__ void k_readout_fin(const float* __restrict__ rsum, const u32* __restrict__ rmaxI,
                              int k, float* __restrict__ r) {
  int b = blockIdx.x, c = threadIdx.x;   // 128 threads
  if (c < 64) r[b * 128 + c] += rsum[b * 64 + c] / (float)k;
  else        r[b * 128 + c] += ford_inv(rmaxI[b * 64 + (c - 64)]);
}

__global__ void k_mlp(const float* __restrict__ r,
                      const float* __restrict__ W1, const float* __restrict__ b1,
                      const float* __restrict__ W2, const float* __restrict__ b2,
                      const float* __restrict__ W3, const float* __restrict__ b3,
                      float* __restrict__ out) {
  __shared__ float v0[128], v1[64], v2[64], lgts[16];
  int b = blockIdx.x, t = threadIdx.x;   // 64 threads
  v0[t] = r[b * 128 + t];
  v0[64 + t] = r[b * 128 + 64 + t];
  __syncthreads();
  float a = b1[t];
  for (int i = 0; i < 128; ++i) a += v0[i] * W1[i * 64 + t];
  v1[t] = fmaxf(a, 0.f);
  __syncthreads();
  a = b2[t];
  for (int i = 0; i < 64; ++i) a += v1[i] * W2[i * 64 + t];
  v2[t] = fmaxf(a, 0.f);
  __syncthreads();
  if (t < 16) {
    a = b3[t];
    for (int i = 0; i < 64; ++i) a += v2[i] * W3[i * 16 + t];
    lgts[t] = a;
  }
  __syncthreads();
  if (t == 0) {
    float m = lgts[0];
    for (int j = 1; j < 16; ++j) m = fmaxf(m, lgts[j]);
    float ex[16], sum = 0.f;
    for (int j = 0; j < 16; ++j) { ex[j] = expf(lgts[j] - m); sum += ex[j]; }
    for (int j = 0; j < 16; ++j) out[b * 16 + j] = ex[j] / sum;
  }
}

extern "C" void kernel_launch(void* const* d_in, const int* in_sizes, int n_in,
                              void* d_out, int out_size, void* d_ws, size_t ws_size,
                              hipStream_t stream) {
  (void)in_sizes; (void)n_in; (void)out_size; (void)ws_size;
  const float* x  = (const float*)d_in[0];      // [NMAX, 32] f32
  const float* ea = (const float*)d_in[1];      // [E, 8]     f32
  const int*   ei = (const int*)d_in[2];        // [2, E]

  const float *gWl[3], *gbl[3], *gWr[3], *gbr[3], *gWe[3], *gatt[3], *gb[3], *pw[3];
  for (int l = 0; l < 3; ++l) {
    int p0 = 4 + 7 * l;
    gWl[l]  = (const float*)d_in[p0 + 0];
    gbl[l]  = (const float*)d_in[p0 + 1];
    gWr[l]  = (const float*)d_in[p0 + 2];
    gbr[l]  = (const float*)d_in[p0 + 3];
    gWe[l]  = (const float*)d_in[p0 + 4];
    gatt[l] = (const float*)d_in[p0 + 5];
    gb[l]   = (const float*)d_in[p0 + 6];
    pw[l]   = (const float*)d_in[25 + l];
  }
  const float* fc1W = (const float*)d_in[28];
  const float* fc1b = (const float*)d_in[29];
  const float* fc2W = (const float*)d_in[30];
  const float* fc2b = (const float*)d_in[31];
  const float* fc3W = (const float*)d_in[32];
  const float* fc3b = (const float*)d_in[33];

  // ---- workspace carve (~136.9 MB; ws >= 138.4 MB proven by round-5 gate) ----
  char* w = (char*)d_ws;
  size_t off = 0;
  auto alloc = [&](size_t bytes) -> void* {
    void* p = w + off;
    off += (bytes + 255) & ~(size_t)255;
    return p;
  };
  float* hbuf = (float*)alloc((size_t)B_ * 1268 * 64 * 4); // pooled features (max K1)
  float* xl   = (float*)alloc((size_t)NMAX * 256 * 4);     // source transform [N,256]
  float* xr   = (float*)alloc((size_t)NMAX * 256 * 4);     // target transform [N,256]
  float* nacc = (float*)alloc((size_t)NMAX * 64 * 4);      // fused GAT output (pre-pool)
  char*  zblk = (char*)alloc((size_t)NMAX * 4 + 32 * 128 * 4); // zeroed per layer
  int*   cnt  = (int*)zblk;
  float* rsum = (float*)(zblk + (size_t)NMAX * 4);
  u32*   rmaxI= (u32*)(zblk + (size_t)NMAX * 4 + 32 * 64 * 4);
  size_t zbytes = (size_t)NMAX * 4 + 32 * 128 * 4;
  int*   csr  = (int*)alloc((size_t)NMAX * MAXDEG * 4);
  float* sbuf = (float*)alloc((size_t)NMAX * 4);
  float* rbuf = (float*)alloc(32 * 128 * 4);
  int* src    = (int*)alloc((size_t)E_TOT * 4);
  int* dst    = (int*)alloc((size_t)E_TOT * 4);
  int* em     = (int*)alloc((size_t)E_TOT * 4);
  int* new_id = (int*)alloc((size_t)NMAX * 4);
  int* perm   = (int*)alloc((size_t)32 * 1268 * 4);

  k_edge_init<<<CDIV(E_TOT, 256), 256, 0, stream>>>(ei, src, dst, em);
  hipMemsetAsync(rbuf, 0, 32 * 128 * 4, stream);

  const int Ns[3]    = {50688, 40576, 32480};   // B*N0, B*K1, B*K2 (all %8==0)
  const int npers[3] = {1584, 1268, 1015};
  const int ks[3]    = {1268, 1015, 812};
  const int npads[3] = {2048, 2048, 1024};

  for (int l = 0; l < 3; ++l) {
    int N = Ns[l];
    const float* hin = (l == 0) ? x : hbuf;
    hipMemsetAsync(zblk, 0, zbytes, stream);
    if (l == 0)
      k_transform_t<32><<<N / 8, 256, 0, stream>>>(hin, gWl[l], gbl[l], gWr[l], gbr[l], xl, xr);
    else
      k_transform_t<64><<<N / 8, 256, 0, stream>>>(hin, gWl[l], gbl[l], gWr[l], gbr[l], xl, xr);
    k_csr_build<<<CDIV(E_TOT, 256), 256, 0, stream>>>(dst, em, cnt, csr);
    k_gat_fused<<<N / 4, 256, 0, stream>>>(src, cnt, csr, ea, gWe[l], gatt[l],
                                           xl, xr, gb[l], pw[l], nacc, sbuf, N);
    k_topk<<<32, 1024, 0, stream>>>(sbuf, npers[l], ks[l], npads[l], perm, new_id);
    k_gather<<<CDIV(B_ * ks[l] * 64, 256), 256, 0, stream>>>(nacc, sbuf, perm, hbuf,
                                                             B_ * ks[l] * 64);
    k_remap<<<CDIV(E_TOT, 256), 256, 0, stream>>>(src, dst, em, new_id);
    k_readout_part<<<dim3(32, 16), 256, 0, stream>>>(hbuf, ks[l], rsum, rmaxI);
    k_readout_fin<<<32, 128, 0, stream>>>(rsum, rmaxI, ks[l], rbuf);
  }
  k_mlp<<<32, 64, 0, stream>>>(rbuf, fc1W, fc1b, fc2W, fc2b, fc3W, fc3b, (float*)d_out);
}

// Round 10
// 562.405 us; speedup vs baseline: 1.9521x; 1.0570x over previous
//
#include <hip/hip_runtime.h>

typedef unsigned short u16;
typedef unsigned int u32;
typedef unsigned long long u64;

#define E_TOT 202752   // B*N0*DEG = 32*1584*4
#define NMAX  50688    // B*N0
#define HEADS 4
#define B_    32
#define MAXDEG 32      // Poisson(4) in-degree: P(>=32) ~ 1e-18/node — safe bucket

#define CDIV(a,b) (((a)+(b)-1)/(b))

// order-preserving float->uint map (monotonic); code 0 is below any real float's code
__device__ __forceinline__ u32 ford(float f) {
  u32 u = __float_as_uint(f);
  return (u & 0x80000000u) ? ~u : (u | 0x80000000u);
}
__device__ __forceinline__ float ford_inv(u32 u) {
  u32 b = (u & 0x80000000u) ? (u ^ 0x80000000u) : ~u;
  return __uint_as_float(b);
}

// edge arrays + CSR for layer 0 in one pass (cnt pre-zeroed)
__global__ void k_edge_init_csr(const int* __restrict__ ei, int* __restrict__ src,
                                int* __restrict__ dst, int* __restrict__ em,
                                int* __restrict__ cnt, int* __restrict__ csr) {
  int e = blockIdx.x * blockDim.x + threadIdx.x;
  if (e >= E_TOT) return;
  int s = ei[e], d = ei[E_TOT + e];
  src[e] = s;
  dst[e] = d;
  em[e] = 1;
  int pos = atomicAdd(&cnt[d], 1);
  if (pos < MAXDEG) csr[d * MAXDEG + pos] = e;
}

// ---------- node transform, 8 nodes/block, W columns reused in regs ----------
template <int FIN>
__global__ void k_transform_t(const float* __restrict__ hin,
                              const float* __restrict__ Wl, const float* __restrict__ bl,
                              const float* __restrict__ Wr, const float* __restrict__ br,
                              float* __restrict__ xl, float* __restrict__ xr) {
  __shared__ float xs[8][FIN];
  int n0 = blockIdx.x * 8, j = threadIdx.x;   // 256 threads
  for (int t = j; t < 8 * FIN; t += 256)
    xs[t >> (FIN == 32 ? 5 : 6)][t & (FIN - 1)] =
        hin[(size_t)(n0 + (t >> (FIN == 32 ? 5 : 6))) * FIN + (t & (FIN - 1))];
  __syncthreads();
  float al[8], ar[8];
  float blv = bl[j], brv = br[j];
#pragma unroll
  for (int t = 0; t < 8; ++t) { al[t] = blv; ar[t] = brv; }
  for (int i = 0; i < FIN; ++i) {
    float wl = Wl[i * 256 + j], wr = Wr[i * 256 + j];
#pragma unroll
    for (int t = 0; t < 8; ++t) {
      float xv = xs[t][i];
      al[t] += xv * wl;
      ar[t] += xv * wr;
    }
  }
#pragma unroll
  for (int t = 0; t < 8; ++t) {
    xl[(size_t)(n0 + t) * 256 + j] = al[t];
    xr[(size_t)(n0 + t) * 256 + j] = ar[t];
  }
}

// ---------- fused GATv2 per dst node, prefetched CSR + 4-edge chunked loads ----------
// one 64-lane wave per node; lane = (head h = lane>>4, chan-group cg = lane&15)
__global__ void k_gat_fused(const int* __restrict__ srcv, const int* __restrict__ cnt,
                            const int* __restrict__ csr, const float* __restrict__ ea,
                            const float* __restrict__ We, const float* __restrict__ att,
                            const float* __restrict__ xl, const float* __restrict__ xr,
                            const float* __restrict__ bias, const float* __restrict__ pwv,
                            float* __restrict__ out, float* __restrict__ sc, int N) {
  int n = blockIdx.x * 4 + (threadIdx.x >> 6);   // 4 waves/block (N%4==0)
  int lane = threadIdx.x & 63;
  int cg = lane & 15;
  int cb = (lane >> 4) * 64 + cg * 4;            // this lane's 4 channels
  if (n >= N) return;
  int deg = min(cnt[n], MAXDEG);
  // lane-parallel prefetch of edge ids + src ids (breaks the per-edge dep chain)
  int e_l = 0, s_l = 0;
  if (lane < deg) { e_l = csr[n * MAXDEG + lane]; s_l = srcv[e_l]; }
  float4 xd4 = *(const float4*)(xr + (size_t)n * 256 + cb);
  float4 at4 = *(const float4*)(att + cb);
  float4 w0 = *(const float4*)(We + 0 * 256 + cb);
  float4 w1 = *(const float4*)(We + 1 * 256 + cb);
  float4 w2 = *(const float4*)(We + 2 * 256 + cb);
  float4 w3 = *(const float4*)(We + 3 * 256 + cb);
  float4 w4_ = *(const float4*)(We + 4 * 256 + cb);
  float4 w5 = *(const float4*)(We + 5 * 256 + cb);
  float4 w6 = *(const float4*)(We + 6 * 256 + cb);
  float4 w7 = *(const float4*)(We + 7 * 256 + cb);
  float m = -INFINITY, l = 0.f;
  float ox = 0.f, oy = 0.f, oz = 0.f, ow = 0.f;
  for (int i0 = 0; i0 < deg; i0 += 4) {
    int c0 = deg - i0; if (c0 > 4) c0 = 4;       // wave-uniform
    float4 xs[4], a0[4], a1[4];
#pragma unroll
    for (int j = 0; j < 4; ++j) {
      int idx = (j < c0) ? (i0 + j) : i0;        // clamp to a safe slot
      int e = __shfl(e_l, idx, 64);
      int s = __shfl(s_l, idx, 64);
      xs[j] = *(const float4*)(xl + (size_t)s * 256 + cb);   // independent, all in flight
      a0[j] = *(const float4*)(ea + (size_t)e * 8);
      a1[j] = *(const float4*)(ea + (size_t)e * 8 + 4);
    }
#pragma unroll
    for (int j = 0; j < 4; ++j) {
      if (j < c0) {
        float e0 = a0[j].x * w0.x + a0[j].y * w1.x + a0[j].z * w2.x + a0[j].w * w3.x
                 + a1[j].x * w4_.x + a1[j].y * w5.x + a1[j].z * w6.x + a1[j].w * w7.x;
        float e1 = a0[j].x * w0.y + a0[j].y * w1.y + a0[j].z * w2.y + a0[j].w * w3.y
                 + a1[j].x * w4_.y + a1[j].y * w5.y + a1[j].z * w6.y + a1[j].w * w7.y;
        float e2 = a0[j].x * w0.z + a0[j].y * w1.z + a0[j].z * w2.z + a0[j].w * w3.z
                 + a1[j].x * w4_.z + a1[j].y * w5.z + a1[j].z * w6.z + a1[j].w * w7.z;
        float e3 = a0[j].x * w0.w + a0[j].y * w1.w + a0[j].z * w2.w + a0[j].w * w3.w
                 + a1[j].x * w4_.w + a1[j].y * w5.w + a1[j].z * w6.w + a1[j].w * w7.w;
        float m0 = xs[j].x + xd4.x + e0; m0 = (m0 >= 0.f) ? m0 : 0.2f * m0;  // leaky 0.2
        float m1 = xs[j].y + xd4.y + e1; m1 = (m1 >= 0.f) ? m1 : 0.2f * m1;
        float m2 = xs[j].z + xd4.z + e2; m2 = (m2 >= 0.f) ? m2 : 0.2f * m2;
        float m3 = xs[j].w + xd4.w + e3; m3 = (m3 >= 0.f) ? m3 : 0.2f * m3;
        float v = at4.x * m0 + at4.y * m1 + at4.z * m2 + at4.w * m3;
        v += __shfl_xor(v, 1, 64);
        v += __shfl_xor(v, 2, 64);
        v += __shfl_xor(v, 4, 64);
        v += __shfl_xor(v, 8, 64);     // all 16 head-lanes hold the head logit
        float nm = fmaxf(m, v);
        float scale = __expf(m - nm);  // exp(-inf - x) = 0 handles first edge
        float p = __expf(v - nm);
        ox = ox * scale + p * xs[j].x;
        oy = oy * scale + p * xs[j].y;
        oz = oz * scale + p * xs[j].z;
        ow = ow * scale + p * xs[j].w;
        l = l * scale + p;
        m = nm;
      }
    }
  }
  // per-head y = O/den, then 0.25 * head-sum  (deg==0 -> l=0 -> y=0, matches ref)
  float inv = 0.25f / fmaxf(l, 1e-16f);
  float r0 = ox * inv, r1 = oy * inv, r2 = oz * inv, r3 = ow * inv;
  r0 += __shfl_xor(r0, 16, 64); r0 += __shfl_xor(r0, 32, 64);
  r1 += __shfl_xor(r1, 16, 64); r1 += __shfl_xor(r1, 32, 64);
  r2 += __shfl_xor(r2, 16, 64); r2 += __shfl_xor(r2, 32, 64);
  r3 += __shfl_xor(r3, 16, 64); r3 += __shfl_xor(r3, 32, 64);
  float4 bi4 = *(const float4*)(bias + cg * 4);
  r0 = fmaxf(r0 + bi4.x, 0.f); r1 = fmaxf(r1 + bi4.y, 0.f);
  r2 = fmaxf(r2 + bi4.z, 0.f); r3 = fmaxf(r3 + bi4.w, 0.f);
  if (lane < 16) *(float4*)(out + (size_t)n * 64 + cg * 4) = float4{r0, r1, r2, r3};
  // topk score: s = tanh(h.w / ||w||)
  float4 pw4 = *(const float4*)(pwv + cg * 4);
  float dot = r0 * pw4.x + r1 * pw4.y + r2 * pw4.z + r3 * pw4.w;
  float wn = pw4.x * pw4.x + pw4.y * pw4.y + pw4.z * pw4.z + pw4.w * pw4.w;
  dot += __shfl_xor(dot, 1, 64); wn += __shfl_xor(wn, 1, 64);
  dot += __shfl_xor(dot, 2, 64); wn += __shfl_xor(wn, 2, 64);
  dot += __shfl_xor(dot, 4, 64); wn += __shfl_xor(wn, 4, 64);
  dot += __shfl_xor(dot, 8, 64); wn += __shfl_xor(wn, 8, 64);
  if (lane == 0) sc[n] = tanhf(dot / sqrtf(wn));
}

// stable descending sort per graph — u64 keys (ford(score)<<32 | ~idx), bitonic <=2048
__global__ __launch_bounds__(1024) void k_topk(const float* __restrict__ s, int n_per,
                                               int k, int npad,
                                               int* __restrict__ perm, int* __restrict__ new_id) {
  __shared__ u64 kv[2048];
  int b = blockIdx.x, tid = threadIdx.x;
  int base = b * n_per;
  for (int i = tid; i < n_per; i += 1024) new_id[base + i] = -1;
  for (int i = tid; i < npad; i += 1024) {
    u32 sk = (i < n_per) ? ford(s[base + i]) : 0u;   // pad key 0: below every real code
    kv[i] = ((u64)sk << 32) | (u32)(0xFFFFFFFFu - (u32)i);   // tie -> lower idx first
  }
  __syncthreads();
  for (int kk = 2; kk <= npad; kk <<= 1) {
    for (int j = kk >> 1; j > 0; j >>= 1) {
      for (int i = tid; i < npad; i += 1024) {
        int ixj = i ^ j;
        if (ixj > i) {
          u64 a = kv[i], c = kv[ixj];
          bool after = a < c;                        // descending order
          bool doswap = ((i & kk) == 0) ? after : !after;
          if (doswap) { kv[i] = c; kv[ixj] = a; }
        }
      }
      __syncthreads();
    }
  }
  for (int r = tid; r < k; r += 1024) {
    int old = (int)(0xFFFFFFFFu - (u32)(kv[r] & 0xFFFFFFFFu));
    perm[b * k + r] = base + old;
    new_id[base + old] = b * k + r;
  }
}

__global__ void k_gather(const float* __restrict__ hin, const float* __restrict__ s,
                         const int* __restrict__ perm, float* __restrict__ hout, int n64) {
  int t = blockIdx.x * blockDim.x + threadIdx.x;
  if (t >= n64) return;
  int i = t >> 6, c = t & 63;
  int g = perm[i];
  hout[t] = hin[(size_t)g * 64 + c] * s[g];
}

// remap edges AND build next layer's CSR (cnt pre-zeroed)
__global__ void k_remap_csr(int* __restrict__ src, int* __restrict__ dst,
                            int* __restrict__ em, const int* __restrict__ new_id,
                            int* __restrict__ cnt, int* __restrict__ csr) {
  int e = blockIdx.x * blockDim.x + threadIdx.x;
  if (e >= E_TOT) return;
  int ns = new_id[src[e]], nd = new_id[dst[e]];
  int m = em[e] && ns >= 0 && nd >= 0;
  src[e] = m ? ns : 0;
  dst[e] = m ? nd : 0;
  em[e] = m;
  if (m) {
    int pos = atomicAdd(&cnt[nd], 1);
    if (pos < MAXDEG) csr[nd * MAXDEG + pos] = e;
  }
}

// chunked parallel readout: grid (B, 16), 256 thr
__global__ void k_readout_part(const float* __restrict__ h, int k,
                               float* __restrict__ rsum, u32* __restrict__ rmaxI) {
  __shared__ float ps[256], pm[256];
  int b = blockIdx.x, ch = blockIdx.y, t = threadIdx.x;
  int c = t & 63, rg = t >> 6;
  int rpc = (k + 15) >> 4;
  int start = ch * rpc, end = min(k, start + rpc);
  const float* hb = h + (size_t)b * k * 64;
  float sum = 0.f, mx = -INFINITY;
  for (int i = start + rg; i < end; i += 4) {
    float v = hb[(size_t)i * 64 + c];
    sum += v;
    mx = fmaxf(mx, v);
  }
  ps[t] = sum; pm[t] = mx;
  __syncthreads();
  if (t < 64) {
    float s4 = ps[t] + ps[t + 64] + ps[t + 128] + ps[t + 192];
    float m4 = fmaxf(fmaxf(pm[t], pm[t + 64]), fmaxf(pm[t + 128], pm[t + 192]));
    atomicAdd(&rsum[b * 64 + t], s4);
    atomicMax(&rmaxI[b * 64 + t], ford(m4));
  }
}

__global__ void k_readout_fin(const float* __restrict__ rsum, const u32* __restrict__ rmaxI,
                              int k, float* __restrict__ r) {
  int b = blockIdx.x, c = threadIdx.x;   // 128 threads
  if (c < 64) r[b * 128 + c] += rsum[b * 64 + c] / (float)k;
  else        r[b * 128 + c] += ford_inv(rmaxI[b * 64 + (c - 64)]);
}

__global__ void k_mlp(const float* __restrict__ r,
                      const float* __restrict__ W1, const float* __restrict__ b1,
                      const float* __restrict__ W2, const float* __restrict__ b2,
                      const float* __restrict__ W3, const float* __restrict__ b3,
                      float* __restrict__ out) {
  __shared__ float v0[128], v1[64], v2[64], lgts[16];
  int b = blockIdx.x, t = threadIdx.x;   // 64 threads
  v0[t] = r[b * 128 + t];
  v0[64 + t] = r[b * 128 + 64 + t];
  __syncthreads();
  float a = b1[t];
  for (int i = 0; i < 128; ++i) a += v0[i] * W1[i * 64 + t];
  v1[t] = fmaxf(a, 0.f);
  __syncthreads();
  a = b2[t];
  for (int i = 0; i < 64; ++i) a += v1[i] * W2[i * 64 + t];
  v2[t] = fmaxf(a, 0.f);
  __syncthreads();
  if (t < 16) {
    a = b3[t];
    for (int i = 0; i < 64; ++i) a += v2[i] * W3[i * 16 + t];
    lgts[t] = a;
  }
  __syncthreads();
  if (t == 0) {
    float m = lgts[0];
    for (int j = 1; j < 16; ++j) m = fmaxf(m, lgts[j]);
    float ex[16], sum = 0.f;
    for (int j = 0; j < 16; ++j) { ex[j] = expf(lgts[j] - m); sum += ex[j]; }
    for (int j = 0; j < 16; ++j) out[b * 16 + j] = ex[j] / sum;
  }
}

extern "C" void kernel_launch(void* const* d_in, const int* in_sizes, int n_in,
                              void* d_out, int out_size, void* d_ws, size_t ws_size,
                              hipStream_t stream) {
  (void)in_sizes; (void)n_in; (void)out_size; (void)ws_size;
  const float* x  = (const float*)d_in[0];      // [NMAX, 32] f32
  const float* ea = (const float*)d_in[1];      // [E, 8]     f32
  const int*   ei = (const int*)d_in[2];        // [2, E]

  const float *gWl[3], *gbl[3], *gWr[3], *gbr[3], *gWe[3], *gatt[3], *gb[3], *pw[3];
  for (int l = 0; l < 3; ++l) {
    int p0 = 4 + 7 * l;
    gWl[l]  = (const float*)d_in[p0 + 0];
    gbl[l]  = (const float*)d_in[p0 + 1];
    gWr[l]  = (const float*)d_in[p0 + 2];
    gbr[l]  = (const float*)d_in[p0 + 3];
    gWe[l]  = (const float*)d_in[p0 + 4];
    gatt[l] = (const float*)d_in[p0 + 5];
    gb[l]   = (const float*)d_in[p0 + 6];
    pw[l]   = (const float*)d_in[25 + l];
  }
  const float* fc1W = (const float*)d_in[28];
  const float* fc1b = (const float*)d_in[29];
  const float* fc2W = (const float*)d_in[30];
  const float* fc2b = (const float*)d_in[31];
  const float* fc3W = (const float*)d_in[32];
  const float* fc3b = (const float*)d_in[33];

  // ---- workspace carve (~136.9 MB; fits per round-5 gate) ----
  char* w = (char*)d_ws;
  size_t off = 0;
  auto alloc = [&](size_t bytes) -> void* {
    void* p = w + off;
    off += (bytes + 255) & ~(size_t)255;
    return p;
  };
  float* hbuf = (float*)alloc((size_t)B_ * 1268 * 64 * 4); // pooled features (max K1)
  float* xl   = (float*)alloc((size_t)NMAX * 256 * 4);     // source transform [N,256]
  float* xr   = (float*)alloc((size_t)NMAX * 256 * 4);     // target transform [N,256]
  float* nacc = (float*)alloc((size_t)NMAX * 64 * 4);      // fused GAT output (pre-pool)
  int*   cnt  = (int*)alloc((size_t)NMAX * 4);             // CSR degree counters
  char*  rblk = (char*)alloc(32 * 128 * 4);                // [rsum 8KB][rmaxI 8KB], per layer
  float* rsum = (float*)rblk;
  u32*   rmaxI= (u32*)(rblk + 32 * 64 * 4);
  int*   csr  = (int*)alloc((size_t)NMAX * MAXDEG * 4);
  float* sbuf = (float*)alloc((size_t)NMAX * 4);
  float* rbuf = (float*)alloc(32 * 128 * 4);
  int* src    = (int*)alloc((size_t)E_TOT * 4);
  int* dst    = (int*)alloc((size_t)E_TOT * 4);
  int* em     = (int*)alloc((size_t)E_TOT * 4);
  int* new_id = (int*)alloc((size_t)NMAX * 4);
  int* perm   = (int*)alloc((size_t)32 * 1268 * 4);

  hipMemsetAsync(cnt, 0, (size_t)NMAX * 4, stream);
  k_edge_init_csr<<<CDIV(E_TOT, 256), 256, 0, stream>>>(ei, src, dst, em, cnt, csr);
  hipMemsetAsync(rbuf, 0, 32 * 128 * 4, stream);

  const int Ns[3]    = {50688, 40576, 32480};   // B*N0, B*K1, B*K2 (all %8==0)
  const int npers[3] = {1584, 1268, 1015};
  const int ks[3]    = {1268, 1015, 812};
  const int npads[3] = {2048, 2048, 1024};

  for (int l = 0; l < 3; ++l) {
    int N = Ns[l];
    const float* hin = (l == 0) ? x : hbuf;
    hipMemsetAsync(rblk, 0, 32 * 128 * 4, stream);
    if (l == 0)
      k_transform_t<32><<<N / 8, 256, 0, stream>>>(hin, gWl[l], gbl[l], gWr[l], gbr[l], xl, xr);
    else
      k_transform_t<64><<<N / 8, 256, 0, stream>>>(hin, gWl[l], gbl[l], gWr[l], gbr[l], xl, xr);
    k_gat_fused<<<N / 4, 256, 0, stream>>>(src, cnt, csr, ea, gWe[l], gatt[l],
                                           xl, xr, gb[l], pw[l], nacc, sbuf, N);
    k_topk<<<32, 1024, 0, stream>>>(sbuf, npers[l], ks[l], npads[l], perm, new_id);
    k_gather<<<CDIV(B_ * ks[l] * 64, 256), 256, 0, stream>>>(nacc, sbuf, perm, hbuf,
                                                             B_ * ks[l] * 64);
    if (l < 2) {
      hipMemsetAsync(cnt, 0, (size_t)NMAX * 4, stream);
      k_remap_csr<<<CDIV(E_TOT, 256), 256, 0, stream>>>(src, dst, em, new_id, cnt, csr);
    }
    k_readout_part<<<dim3(32, 16), 256, 0, stream>>>(hbuf, ks[l], rsum, rmaxI);
    k_readout_fin<<<32, 128, 0, stream>>>(rsum, rmaxI, ks[l], rbuf);
  }
  k_mlp<<<32, 64, 0, stream>>>(rbuf, fc1W, fc1b, fc2W, fc2b, fc3W, fc3b, (float*)d_out);
}